// Round 3
// baseline (463.994 us; speedup 1.0000x reference)
//
#include <hip/hip_runtime.h>
#include <hip/hip_bf16.h>
#include <math.h>

// Problem constants (from reference setup_inputs)
#define BB 32
#define NN 1024
#define DD 64
#define TT 2048
#define CHUNKS (TT / 256)   // 8 column-chunks of 256
#define SEGS 16             // n-segments (decoupled scan)

typedef float f32x4 __attribute__((ext_vector_type(4)));

// Pin 16 f32x4 (the 64-float W column) into live VGPRs: the empty asm
// "redefines" them every iteration, so the compiler can't remat-reload W
// from memory or park the values in AGPRs (which costs a v_accvgpr_read
// per use). Zero instructions emitted.
#define PIN_W(Wv) asm volatile("" \
    : "+v"(Wv[0]), "+v"(Wv[1]), "+v"(Wv[2]),  "+v"(Wv[3]),  \
      "+v"(Wv[4]), "+v"(Wv[5]), "+v"(Wv[6]),  "+v"(Wv[7]),  \
      "+v"(Wv[8]), "+v"(Wv[9]), "+v"(Wv[10]), "+v"(Wv[11]), \
      "+v"(Wv[12]),"+v"(Wv[13]),"+v"(Wv[14]), "+v"(Wv[15]))

template<int CTRL>
__device__ __forceinline__ float dpp_mov_f(float v) {
    int i = __builtin_amdgcn_update_dpp(__float_as_int(v), __float_as_int(v),
                                        CTRL, 0xF, 0xF, false);
    return __int_as_float(i);
}

// All-lanes butterfly reduce over groups of 2^GB lanes.
// GB=4: pure-VALU DPP (xor1, xor2, half-mirror=xor4, mirror=xor8).
// GB=6: adds two LDS shuffles (xor16, xor32).
template<int GB>
__device__ __forceinline__ float groupMax(float v) {
    v = fmaxf(v, dpp_mov_f<0x0B1>(v));  // quad_perm [1,0,3,2]  -> xor1
    v = fmaxf(v, dpp_mov_f<0x04E>(v));  // quad_perm [2,3,0,1]  -> xor2
    v = fmaxf(v, dpp_mov_f<0x141>(v));  // row_half_mirror      -> xor4
    v = fmaxf(v, dpp_mov_f<0x140>(v));  // row_mirror           -> xor8
    if constexpr (GB == 6) {
        v = fmaxf(v, __shfl_xor(v, 16));
        v = fmaxf(v, __shfl_xor(v, 32));
    }
    return v;
}

template<int GB>
__device__ __forceinline__ float groupSum(float v) {
    v += dpp_mov_f<0x0B1>(v);
    v += dpp_mov_f<0x04E>(v);
    v += dpp_mov_f<0x141>(v);
    v += dpp_mov_f<0x140>(v);
    if constexpr (GB == 6) {
        v += __shfl_xor(v, 16);
        v += __shfl_xor(v, 32);
    }
    return v;
}

// dot(x_row, w): same FP association as R2's dot64 -> identical numerics.
__device__ __forceinline__ float dot64v(const f32x4* __restrict__ xr,
                                        const f32x4* wv) {
    float a0 = 0.f, a1 = 0.f, a2 = 0.f, a3 = 0.f;
#pragma unroll
    for (int i = 0; i < 16; ++i) {
        const f32x4 x = xr[i];   // uniform address -> scalar loads
        a0 = fmaf(x.x, wv[i].x, a0);
        a1 = fmaf(x.y, wv[i].y, a1);
        a2 = fmaf(x.z, wv[i].z, a2);
        a3 = fmaf(x.w, wv[i].w, a3);
    }
    return (a0 + a1) + (a2 + a3);
}

__device__ __forceinline__ void loadW(const float* __restrict__ W, int col,
                                      f32x4* wv) {
#pragma unroll
    for (int i = 0; i < 16; ++i) {
        wv[i].x = W[(size_t)(4 * i + 0) * TT + col];
        wv[i].y = W[(size_t)(4 * i + 1) * TT + col];
        wv[i].z = W[(size_t)(4 * i + 2) * TT + col];
        wv[i].w = W[(size_t)(4 * i + 3) * TT + col];
    }
}

// Pass A: per-(b, t, segment) sum of log-probs. Fully parallel over segments.
template<int SEG>
__global__ __launch_bounds__(256, 4)
void segsum_kernel(const float* __restrict__ data,
                   const float* __restrict__ targets,
                   const float* __restrict__ W,
                   float* __restrict__ segsum)
{
    constexpr int NSEG = NN / SEG;
    const int blk   = blockIdx.x;
    const int s     = blk % SEG;
    const int rem   = blk / SEG;
    const int chunk = rem % CHUNKS;
    const int b     = rem / CHUNKS;
    const int tid   = threadIdx.x;
    const int col   = chunk * 256 + tid;

    f32x4 wv[16];
    loadW(W, col, wv);

    const float* xb = data + (size_t)b * NN * DD;
    const float* tb = targets + (size_t)b * NN;

    const int n0 = s * NSEG;
    float acc = 0.0f;
    for (int n = n0; n < n0 + NSEG; ++n) {
        PIN_W(wv);
        const float xw   = dot64v((const f32x4*)(xb + (size_t)n * DD), wv);
        const float diff = tb[n] - xw;
        acc = fmaf(diff * diff, -0.5f, acc);
    }
    segsum[((size_t)b * SEG + s) * TT + col] = acc;
}

// Pass B: per-(b, t-chunk, segment) local scan seeded with segment prefix;
// emits per-2^GB-lane-group softmax partials (m, s, p) for every n.
template<int SEG, int GB>
__global__ __launch_bounds__(256, 4)
void scan_kernel(const float* __restrict__ data,
                 const float* __restrict__ targets,
                 const float* __restrict__ W,
                 const float* __restrict__ segsum,
                 float* __restrict__ mP,
                 float* __restrict__ sP,
                 float* __restrict__ pP)
{
    constexpr int NSEG = NN / SEG;
    constexpr int PPN  = TT >> GB;            // partials per (b,n)
    const int blk   = blockIdx.x;
    const int s     = blk % SEG;
    const int rem   = blk / SEG;
    const int chunk = rem % CHUNKS;
    const int b     = rem / CHUNKS;
    const int tid   = threadIdx.x;
    const int lane  = tid & 63;
    const int col   = chunk * 256 + tid;

    f32x4 wv[16];
    loadW(W, col, wv);

    const float* xb = data + (size_t)b * NN * DD;
    const float* tb = targets + (size_t)b * NN;

    const int  k      = (chunk * 256 + (tid & ~((1 << GB) - 1))) >> GB;
    const bool writer = (lane & ((1 << GB) - 1)) == 0;
    const size_t base0 = (size_t)b * NN * PPN + k;

    // exclusive segment prefix
    float alpha = 0.0f;
    if constexpr (SEG > 1) {
        for (int s2 = 0; s2 < s; ++s2)
            alpha += segsum[((size_t)b * SEG + s2) * TT + col];
    }

    const int n0 = s * NSEG;
    for (int n = n0; n < n0 + NSEG; ++n) {
        PIN_W(wv);
        const float xw = dot64v((const f32x4*)(xb + (size_t)n * DD), wv);

        // exclusive-prefix softmax partials (alpha BEFORE adding point n)
        const float m  = groupMax<GB>(alpha);
        const float e  = __expf(alpha - m);
        const float pe = e * xw;
        const float sv = groupSum<GB>(e);
        const float pv = groupSum<GB>(pe);

        if (writer) {
            const size_t idx = base0 + (size_t)n * PPN;
            mP[idx] = m; sP[idx] = sv; pP[idx] = pv;
        }

        const float diff = tb[n] - xw;
        alpha = fmaf(diff * diff, -0.5f, alpha);
    }
}

// Pass C: one wave per (b,n): merge PPN partials with log-sum-exp combine.
template<int PPN>
__global__ __launch_bounds__(256)
void combine_kernel(const float* __restrict__ mP,
                    const float* __restrict__ sP,
                    const float* __restrict__ pP,
                    float* __restrict__ out)
{
    const int wgid = blockIdx.x * 4 + (threadIdx.x >> 6);   // = b*NN + n
    const int lane = threadIdx.x & 63;
    const size_t base = (size_t)wgid * PPN;

    float m = -INFINITY, s = 0.0f, p = 0.0f;
    if constexpr (PPN >= 64) {
#pragma unroll
        for (int j = 0; j < PPN / 64; ++j) {
            const size_t idx = base + lane + j * 64;
            const float mk = mP[idx], sk = sP[idx], pk = pP[idx];
            const float M  = fmaxf(m, mk);
            const float e1 = __expf(m - M), e2 = __expf(mk - M);
            s = s * e1 + sk * e2;
            p = p * e1 + pk * e2;
            m = M;
        }
    } else {
        if (lane < PPN) {
            m = mP[base + lane]; s = sP[base + lane]; p = pP[base + lane];
        }
    }

#pragma unroll
    for (int off = 1; off < 64; off <<= 1) {
        const float mo = __shfl_xor(m, off);
        const float so = __shfl_xor(s, off);
        const float po = __shfl_xor(p, off);
        const float M  = fmaxf(m, mo);
        const float e1 = __expf(m - M), e2 = __expf(mo - M);
        s = s * e1 + so * e2;
        p = p * e1 + po * e2;
        m = M;
    }

    if (lane == 0) out[wgid] = p / s;
}

extern "C" void kernel_launch(void* const* d_in, const int* in_sizes, int n_in,
                              void* d_out, int out_size, void* d_ws, size_t ws_size,
                              hipStream_t stream)
{
    (void)in_sizes; (void)n_in; (void)out_size;
    const float* data    = (const float*)d_in[0];
    const float* targets = (const float*)d_in[1];
    const float* W       = (const float*)d_in[2];
    float* out = (float*)d_out;

    const size_t plane4 = (size_t)BB * NN * (TT >> 4);   // GB=4: 128 partials/(b,n)
    const size_t plane6 = (size_t)BB * NN * (TT >> 6);   // GB=6: 32 partials/(b,n)
    const size_t segN   = (size_t)BB * SEGS * TT;

    if (ws_size >= (3 * plane4 + segN) * sizeof(float)) {
        // ~55 MB path: SEG=16, GB=4 (DPP-only reductions)
        float* mP = (float*)d_ws;
        float* sP = mP + plane4;
        float* pP = sP + plane4;
        float* sg = pP + plane4;
        segsum_kernel<SEGS><<<BB * CHUNKS * SEGS, 256, 0, stream>>>(data, targets, W, sg);
        scan_kernel<SEGS, 4><<<BB * CHUNKS * SEGS, 256, 0, stream>>>(data, targets, W, sg, mP, sP, pP);
        combine_kernel<128><<<(BB * NN) / 4, 256, 0, stream>>>(mP, sP, pP, out);
    } else if (ws_size >= (3 * plane6 + segN) * sizeof(float)) {
        // ~17 MB path: SEG=16, GB=6
        float* mP = (float*)d_ws;
        float* sP = mP + plane6;
        float* pP = sP + plane6;
        float* sg = pP + plane6;
        segsum_kernel<SEGS><<<BB * CHUNKS * SEGS, 256, 0, stream>>>(data, targets, W, sg);
        scan_kernel<SEGS, 6><<<BB * CHUNKS * SEGS, 256, 0, stream>>>(data, targets, W, sg, mP, sP, pP);
        combine_kernel<32><<<(BB * NN) / 4, 256, 0, stream>>>(mP, sP, pP, out);
    } else {
        // 12 MB fallback: no segmentation (slow but correct)
        float* mP = (float*)d_ws;
        float* sP = mP + plane6;
        float* pP = sP + plane6;
        scan_kernel<1, 6><<<BB * CHUNKS, 256, 0, stream>>>(data, targets, W, nullptr, mP, sP, pP);
        combine_kernel<32><<<(BB * NN) / 4, 256, 0, stream>>>(mP, sP, pP, out);
    }
}

// Round 4
// 463.551 us; speedup vs baseline: 1.0010x; 1.0010x over previous
//
#include <hip/hip_runtime.h>
#include <hip/hip_bf16.h>
#include <math.h>

// Problem constants (from reference setup_inputs)
#define BB 32
#define NN 1024
#define DD 64
#define TT 2048
#define CHUNKS (TT / 256)   // 8 column-chunks of 256
#define SEGS 16             // n-segments (decoupled scan)

typedef float f32x4 __attribute__((ext_vector_type(4)));

// Pin 16 f32x4 (the 64-float W column) into live VGPRs: the empty asm
// "redefines" them every iteration, so the compiler can't remat-reload W
// from memory. NOTE: needs a >=256-VGPR budget (__launch_bounds__(256,2));
// under a 128-reg cap the 16 aligned quads can't be colored and RA spills
// them to scratch (R3 regression).
#define PIN_W(Wv) asm volatile("" \
    : "+v"(Wv[0]), "+v"(Wv[1]), "+v"(Wv[2]),  "+v"(Wv[3]),  \
      "+v"(Wv[4]), "+v"(Wv[5]), "+v"(Wv[6]),  "+v"(Wv[7]),  \
      "+v"(Wv[8]), "+v"(Wv[9]), "+v"(Wv[10]), "+v"(Wv[11]), \
      "+v"(Wv[12]),"+v"(Wv[13]),"+v"(Wv[14]), "+v"(Wv[15]))

template<int CTRL>
__device__ __forceinline__ float dpp_mov_f(float v) {
    int i = __builtin_amdgcn_update_dpp(__float_as_int(v), __float_as_int(v),
                                        CTRL, 0xF, 0xF, false);
    return __int_as_float(i);
}

// All-lanes butterfly reduce over groups of 2^GB lanes.
// GB=4: pure-VALU DPP (xor1, xor2, half-mirror=xor4, mirror=xor8).
// GB=6: adds two LDS shuffles (xor16, xor32).
template<int GB>
__device__ __forceinline__ float groupMax(float v) {
    v = fmaxf(v, dpp_mov_f<0x0B1>(v));  // quad_perm [1,0,3,2]  -> xor1
    v = fmaxf(v, dpp_mov_f<0x04E>(v));  // quad_perm [2,3,0,1]  -> xor2
    v = fmaxf(v, dpp_mov_f<0x141>(v));  // row_half_mirror      -> xor4
    v = fmaxf(v, dpp_mov_f<0x140>(v));  // row_mirror           -> xor8
    if constexpr (GB == 6) {
        v = fmaxf(v, __shfl_xor(v, 16));
        v = fmaxf(v, __shfl_xor(v, 32));
    }
    return v;
}

template<int GB>
__device__ __forceinline__ float groupSum(float v) {
    v += dpp_mov_f<0x0B1>(v);
    v += dpp_mov_f<0x04E>(v);
    v += dpp_mov_f<0x141>(v);
    v += dpp_mov_f<0x140>(v);
    if constexpr (GB == 6) {
        v += __shfl_xor(v, 16);
        v += __shfl_xor(v, 32);
    }
    return v;
}

// dot(x_row, w): same FP association as R2's dot64 -> identical numerics.
__device__ __forceinline__ float dot64v(const f32x4* __restrict__ xr,
                                        const f32x4* wv) {
    float a0 = 0.f, a1 = 0.f, a2 = 0.f, a3 = 0.f;
#pragma unroll
    for (int i = 0; i < 16; ++i) {
        const f32x4 x = xr[i];   // uniform address -> scalar loads
        a0 = fmaf(x.x, wv[i].x, a0);
        a1 = fmaf(x.y, wv[i].y, a1);
        a2 = fmaf(x.z, wv[i].z, a2);
        a3 = fmaf(x.w, wv[i].w, a3);
    }
    return (a0 + a1) + (a2 + a3);
}

__device__ __forceinline__ void loadW(const float* __restrict__ W, int col,
                                      f32x4* wv) {
#pragma unroll
    for (int i = 0; i < 16; ++i) {
        wv[i].x = W[(size_t)(4 * i + 0) * TT + col];
        wv[i].y = W[(size_t)(4 * i + 1) * TT + col];
        wv[i].z = W[(size_t)(4 * i + 2) * TT + col];
        wv[i].w = W[(size_t)(4 * i + 3) * TT + col];
    }
}

// Pass A: per-(b, t, segment) sum of log-probs. Fully parallel over segments.
template<int SEG>
__global__ __launch_bounds__(256, 2)
void segsum_kernel(const float* __restrict__ data,
                   const float* __restrict__ targets,
                   const float* __restrict__ W,
                   float* __restrict__ segsum)
{
    constexpr int NSEG = NN / SEG;
    const int blk   = blockIdx.x;
    const int s     = blk % SEG;
    const int rem   = blk / SEG;
    const int chunk = rem % CHUNKS;
    const int b     = rem / CHUNKS;
    const int tid   = threadIdx.x;
    const int col   = chunk * 256 + tid;

    f32x4 wv[16];
    loadW(W, col, wv);
    PIN_W(wv);

    const float* xb = data + (size_t)b * NN * DD;
    const float* tb = targets + (size_t)b * NN;

    const int n0 = s * NSEG;
    float acc = 0.0f;
    for (int n = n0; n < n0 + NSEG; ++n) {
        PIN_W(wv);
        const float xw   = dot64v((const f32x4*)(xb + (size_t)n * DD), wv);
        const float diff = tb[n] - xw;
        acc = fmaf(diff * diff, -0.5f, acc);
    }
    segsum[((size_t)b * SEG + s) * TT + col] = acc;
}

// Pass B: per-(b, t-chunk, segment) local scan seeded with segment prefix;
// emits per-2^GB-lane-group softmax partials (m, s, p) for every n.
template<int SEG, int GB>
__global__ __launch_bounds__(256, 2)
void scan_kernel(const float* __restrict__ data,
                 const float* __restrict__ targets,
                 const float* __restrict__ W,
                 const float* __restrict__ segsum,
                 float* __restrict__ mP,
                 float* __restrict__ sP,
                 float* __restrict__ pP)
{
    constexpr int NSEG = NN / SEG;
    constexpr int PPN  = TT >> GB;            // partials per (b,n)
    const int blk   = blockIdx.x;
    const int s     = blk % SEG;
    const int rem   = blk / SEG;
    const int chunk = rem % CHUNKS;
    const int b     = rem / CHUNKS;
    const int tid   = threadIdx.x;
    const int lane  = tid & 63;
    const int col   = chunk * 256 + tid;

    f32x4 wv[16];
    loadW(W, col, wv);
    PIN_W(wv);

    const float* xb = data + (size_t)b * NN * DD;
    const float* tb = targets + (size_t)b * NN;

    const int  k      = (chunk * 256 + (tid & ~((1 << GB) - 1))) >> GB;
    const bool writer = (lane & ((1 << GB) - 1)) == 0;
    const size_t base0 = (size_t)b * NN * PPN + k;

    // exclusive segment prefix
    float alpha = 0.0f;
    if constexpr (SEG > 1) {
        for (int s2 = 0; s2 < s; ++s2)
            alpha += segsum[((size_t)b * SEG + s2) * TT + col];
    }

    const int n0 = s * NSEG;
    for (int n = n0; n < n0 + NSEG; ++n) {
        PIN_W(wv);
        const float xw = dot64v((const f32x4*)(xb + (size_t)n * DD), wv);

        // exclusive-prefix softmax partials (alpha BEFORE adding point n)
        const float m  = groupMax<GB>(alpha);
        const float e  = __expf(alpha - m);
        const float pe = e * xw;
        const float sv = groupSum<GB>(e);
        const float pv = groupSum<GB>(pe);

        if (writer) {
            const size_t idx = base0 + (size_t)n * PPN;
            mP[idx] = m; sP[idx] = sv; pP[idx] = pv;
        }

        const float diff = tb[n] - xw;
        alpha = fmaf(diff * diff, -0.5f, alpha);
    }
}

// Pass C: one wave per (b,n): merge PPN partials with log-sum-exp combine.
template<int PPN>
__global__ __launch_bounds__(256)
void combine_kernel(const float* __restrict__ mP,
                    const float* __restrict__ sP,
                    const float* __restrict__ pP,
                    float* __restrict__ out)
{
    const int wgid = blockIdx.x * 4 + (threadIdx.x >> 6);   // = b*NN + n
    const int lane = threadIdx.x & 63;
    const size_t base = (size_t)wgid * PPN;

    float m = -INFINITY, s = 0.0f, p = 0.0f;
    if constexpr (PPN >= 64) {
#pragma unroll
        for (int j = 0; j < PPN / 64; ++j) {
            const size_t idx = base + lane + j * 64;
            const float mk = mP[idx], sk = sP[idx], pk = pP[idx];
            const float M  = fmaxf(m, mk);
            const float e1 = __expf(m - M), e2 = __expf(mk - M);
            s = s * e1 + sk * e2;
            p = p * e1 + pk * e2;
            m = M;
        }
    } else {
        if (lane < PPN) {
            m = mP[base + lane]; s = sP[base + lane]; p = pP[base + lane];
        }
    }

#pragma unroll
    for (int off = 1; off < 64; off <<= 1) {
        const float mo = __shfl_xor(m, off);
        const float so = __shfl_xor(s, off);
        const float po = __shfl_xor(p, off);
        const float M  = fmaxf(m, mo);
        const float e1 = __expf(m - M), e2 = __expf(mo - M);
        s = s * e1 + so * e2;
        p = p * e1 + po * e2;
        m = M;
    }

    if (lane == 0) out[wgid] = p / s;
}

extern "C" void kernel_launch(void* const* d_in, const int* in_sizes, int n_in,
                              void* d_out, int out_size, void* d_ws, size_t ws_size,
                              hipStream_t stream)
{
    (void)in_sizes; (void)n_in; (void)out_size;
    const float* data    = (const float*)d_in[0];
    const float* targets = (const float*)d_in[1];
    const float* W       = (const float*)d_in[2];
    float* out = (float*)d_out;

    const size_t plane4 = (size_t)BB * NN * (TT >> 4);   // GB=4: 128 partials/(b,n)
    const size_t plane6 = (size_t)BB * NN * (TT >> 6);   // GB=6: 32 partials/(b,n)
    const size_t segN   = (size_t)BB * SEGS * TT;

    if (ws_size >= (3 * plane4 + segN) * sizeof(float)) {
        // ~55 MB path: SEG=16, GB=4 (DPP-only reductions)
        float* mP = (float*)d_ws;
        float* sP = mP + plane4;
        float* pP = sP + plane4;
        float* sg = pP + plane4;
        segsum_kernel<SEGS><<<BB * CHUNKS * SEGS, 256, 0, stream>>>(data, targets, W, sg);
        scan_kernel<SEGS, 4><<<BB * CHUNKS * SEGS, 256, 0, stream>>>(data, targets, W, sg, mP, sP, pP);
        combine_kernel<128><<<(BB * NN) / 4, 256, 0, stream>>>(mP, sP, pP, out);
    } else if (ws_size >= (3 * plane6 + segN) * sizeof(float)) {
        // ~17 MB path: SEG=16, GB=6
        float* mP = (float*)d_ws;
        float* sP = mP + plane6;
        float* pP = sP + plane6;
        float* sg = pP + plane6;
        segsum_kernel<SEGS><<<BB * CHUNKS * SEGS, 256, 0, stream>>>(data, targets, W, sg);
        scan_kernel<SEGS, 6><<<BB * CHUNKS * SEGS, 256, 0, stream>>>(data, targets, W, sg, mP, sP, pP);
        combine_kernel<32><<<(BB * NN) / 4, 256, 0, stream>>>(mP, sP, pP, out);
    } else {
        // 12 MB fallback: no segmentation (slow but correct)
        float* mP = (float*)d_ws;
        float* sP = mP + plane6;
        float* pP = sP + plane6;
        scan_kernel<1, 6><<<BB * CHUNKS, 256, 0, stream>>>(data, targets, W, nullptr, mP, sP, pP);
        combine_kernel<32><<<(BB * NN) / 4, 256, 0, stream>>>(mP, sP, pP, out);
    }
}

// Round 5
// 345.152 us; speedup vs baseline: 1.3443x; 1.3430x over previous
//
#include <hip/hip_runtime.h>
#include <hip/hip_bf16.h>
#include <math.h>

// Problem constants (from reference setup_inputs)
#define BB 32
#define NN 1024
#define DD 64
#define TT 2048
#define CHUNKS (TT / 256)   // 8 column-chunks of 256
#define SEGS 16             // n-segments (decoupled scan)

typedef float f32x4 __attribute__((ext_vector_type(4)));

template<int CTRL>
__device__ __forceinline__ float dpp_mov_f(float v) {
    int i = __builtin_amdgcn_update_dpp(__float_as_int(v), __float_as_int(v),
                                        CTRL, 0xF, 0xF, false);
    return __int_as_float(i);
}

// All-lanes butterfly reduce over groups of 2^GB lanes.
// GB=4: pure-VALU DPP (xor1, xor2, half-mirror=xor4, mirror=xor8).
// GB=6: adds two LDS shuffles (xor16, xor32).
template<int GB>
__device__ __forceinline__ float groupMax(float v) {
    v = fmaxf(v, dpp_mov_f<0x0B1>(v));  // quad_perm [1,0,3,2]  -> xor1
    v = fmaxf(v, dpp_mov_f<0x04E>(v));  // quad_perm [2,3,0,1]  -> xor2
    v = fmaxf(v, dpp_mov_f<0x141>(v));  // row_half_mirror      -> xor4
    v = fmaxf(v, dpp_mov_f<0x140>(v));  // row_mirror           -> xor8
    if constexpr (GB == 6) {
        v = fmaxf(v, __shfl_xor(v, 16));
        v = fmaxf(v, __shfl_xor(v, 32));
    }
    return v;
}

template<int GB>
__device__ __forceinline__ float groupSum(float v) {
    v += dpp_mov_f<0x0B1>(v);
    v += dpp_mov_f<0x04E>(v);
    v += dpp_mov_f<0x141>(v);
    v += dpp_mov_f<0x140>(v);
    if constexpr (GB == 6) {
        v += __shfl_xor(v, 16);
        v += __shfl_xor(v, 32);
    }
    return v;
}

__device__ __forceinline__ void loadW(const float* __restrict__ W, int col,
                                      f32x4* wv) {
#pragma unroll
    for (int i = 0; i < 16; ++i) {
        wv[i].x = W[(size_t)(4 * i + 0) * TT + col];
        wv[i].y = W[(size_t)(4 * i + 1) * TT + col];
        wv[i].z = W[(size_t)(4 * i + 2) * TT + col];
        wv[i].w = W[(size_t)(4 * i + 3) * TT + col];
    }
}

// horizontal sum with the SAME association as the original dot64:
// (a0+a1)+(a2+a3) where a_k accumulated d = k, k+4, k+8, ...
__device__ __forceinline__ float hsum(f32x4 s) {
    return (s.x + s.y) + (s.z + s.w);
}

// 4 independent dots vs the same W column. Element-wise vector FMA
// (fp-contract fuses s += x*w into v_fma) -> per-n FP order identical to
// the scalar dot64. Each wv[i] quad is read ONCE per 16 FMAs, amortizing
// any v_accvgpr_read tax 4x when the compiler parks W in AGPRs.
__device__ __forceinline__ void dot4(const float* __restrict__ x0p,
                                     const f32x4* wv,
                                     float& xw0, float& xw1,
                                     float& xw2, float& xw3) {
    const f32x4* xr0 = (const f32x4*)(x0p);
    const f32x4* xr1 = (const f32x4*)(x0p + DD);
    const f32x4* xr2 = (const f32x4*)(x0p + 2 * DD);
    const f32x4* xr3 = (const f32x4*)(x0p + 3 * DD);
    f32x4 s0 = {0.f, 0.f, 0.f, 0.f};
    f32x4 s1 = {0.f, 0.f, 0.f, 0.f};
    f32x4 s2 = {0.f, 0.f, 0.f, 0.f};
    f32x4 s3 = {0.f, 0.f, 0.f, 0.f};
#pragma unroll
    for (int i = 0; i < 16; ++i) {
        const f32x4 w = wv[i];      // one (possibly AGPR) read, four uses
        s0 += xr0[i] * w;           // uniform x -> scalar loads
        s1 += xr1[i] * w;
        s2 += xr2[i] * w;
        s3 += xr3[i] * w;
    }
    xw0 = hsum(s0); xw1 = hsum(s1); xw2 = hsum(s2); xw3 = hsum(s3);
}

// Pass A: per-(b, t, segment) sum of log-probs. Fully parallel over segments.
template<int SEG>
__global__ __launch_bounds__(256, 4)
void segsum_kernel(const float* __restrict__ data,
                   const float* __restrict__ targets,
                   const float* __restrict__ W,
                   float* __restrict__ segsum)
{
    constexpr int NSEG = NN / SEG;
    const int blk   = blockIdx.x;
    const int s     = blk % SEG;
    const int rem   = blk / SEG;
    const int chunk = rem % CHUNKS;
    const int b     = rem / CHUNKS;
    const int tid   = threadIdx.x;
    const int col   = chunk * 256 + tid;

    f32x4 wv[16];
    loadW(W, col, wv);

    const float* xb = data + (size_t)b * NN * DD;
    const float* tb = targets + (size_t)b * NN;

    const int n0 = s * NSEG;
    float acc = 0.0f;
    for (int n = n0; n < n0 + NSEG; n += 4) {
        float xw0, xw1, xw2, xw3;
        dot4(xb + (size_t)n * DD, wv, xw0, xw1, xw2, xw3);
        const float t0 = tb[n], t1 = tb[n + 1], t2 = tb[n + 2], t3 = tb[n + 3];
        const float d0 = t0 - xw0;  acc = fmaf(d0 * d0, -0.5f, acc);
        const float d1 = t1 - xw1;  acc = fmaf(d1 * d1, -0.5f, acc);
        const float d2 = t2 - xw2;  acc = fmaf(d2 * d2, -0.5f, acc);
        const float d3 = t3 - xw3;  acc = fmaf(d3 * d3, -0.5f, acc);
    }
    segsum[((size_t)b * SEG + s) * TT + col] = acc;
}

// Pass B: per-(b, t-chunk, segment) local scan seeded with segment prefix;
// emits per-2^GB-lane-group softmax partials (m, s, p) for every n.
template<int SEG, int GB>
__global__ __launch_bounds__(256, 4)
void scan_kernel(const float* __restrict__ data,
                 const float* __restrict__ targets,
                 const float* __restrict__ W,
                 const float* __restrict__ segsum,
                 float* __restrict__ mP,
                 float* __restrict__ sP,
                 float* __restrict__ pP)
{
    constexpr int NSEG = NN / SEG;
    constexpr int PPN  = TT >> GB;            // partials per (b,n)
    const int blk   = blockIdx.x;
    const int s     = blk % SEG;
    const int rem   = blk / SEG;
    const int chunk = rem % CHUNKS;
    const int b     = rem / CHUNKS;
    const int tid   = threadIdx.x;
    const int lane  = tid & 63;
    const int col   = chunk * 256 + tid;

    f32x4 wv[16];
    loadW(W, col, wv);

    const float* xb = data + (size_t)b * NN * DD;
    const float* tb = targets + (size_t)b * NN;

    const int  k      = (chunk * 256 + (tid & ~((1 << GB) - 1))) >> GB;
    const bool writer = (lane & ((1 << GB) - 1)) == 0;
    const size_t base0 = (size_t)b * NN * PPN + k;

    // exclusive segment prefix
    float alpha = 0.0f;
    if constexpr (SEG > 1) {
        for (int s2 = 0; s2 < s; ++s2)
            alpha += segsum[((size_t)b * SEG + s2) * TT + col];
    }

    const int n0 = s * NSEG;
    for (int n = n0; n < n0 + NSEG; n += 4) {
        float xw[4];
        dot4(xb + (size_t)n * DD, wv, xw[0], xw[1], xw[2], xw[3]);

#pragma unroll
        for (int j = 0; j < 4; ++j) {
            // exclusive-prefix softmax partials (alpha BEFORE adding point n+j)
            const float m  = groupMax<GB>(alpha);
            const float e  = __expf(alpha - m);
            const float pe = e * xw[j];
            const float sv = groupSum<GB>(e);
            const float pv = groupSum<GB>(pe);

            if (writer) {
                const size_t idx = base0 + (size_t)(n + j) * PPN;
                mP[idx] = m; sP[idx] = sv; pP[idx] = pv;
            }

            const float diff = tb[n + j] - xw[j];
            alpha = fmaf(diff * diff, -0.5f, alpha);
        }
    }
}

// Pass C: one wave per (b,n): merge PPN partials with log-sum-exp combine.
template<int PPN>
__global__ __launch_bounds__(256)
void combine_kernel(const float* __restrict__ mP,
                    const float* __restrict__ sP,
                    const float* __restrict__ pP,
                    float* __restrict__ out)
{
    const int wgid = blockIdx.x * 4 + (threadIdx.x >> 6);   // = b*NN + n
    const int lane = threadIdx.x & 63;
    const size_t base = (size_t)wgid * PPN;

    float m = -INFINITY, s = 0.0f, p = 0.0f;
    if constexpr (PPN >= 64) {
#pragma unroll
        for (int j = 0; j < PPN / 64; ++j) {
            const size_t idx = base + lane + j * 64;
            const float mk = mP[idx], sk = sP[idx], pk = pP[idx];
            const float M  = fmaxf(m, mk);
            const float e1 = __expf(m - M), e2 = __expf(mk - M);
            s = s * e1 + sk * e2;
            p = p * e1 + pk * e2;
            m = M;
        }
    } else {
        if (lane < PPN) {
            m = mP[base + lane]; s = sP[base + lane]; p = pP[base + lane];
        }
    }

#pragma unroll
    for (int off = 1; off < 64; off <<= 1) {
        const float mo = __shfl_xor(m, off);
        const float so = __shfl_xor(s, off);
        const float po = __shfl_xor(p, off);
        const float M  = fmaxf(m, mo);
        const float e1 = __expf(m - M), e2 = __expf(mo - M);
        s = s * e1 + so * e2;
        p = p * e1 + po * e2;
        m = M;
    }

    if (lane == 0) out[wgid] = p / s;
}

extern "C" void kernel_launch(void* const* d_in, const int* in_sizes, int n_in,
                              void* d_out, int out_size, void* d_ws, size_t ws_size,
                              hipStream_t stream)
{
    (void)in_sizes; (void)n_in; (void)out_size;
    const float* data    = (const float*)d_in[0];
    const float* targets = (const float*)d_in[1];
    const float* W       = (const float*)d_in[2];
    float* out = (float*)d_out;

    const size_t plane4 = (size_t)BB * NN * (TT >> 4);   // GB=4: 128 partials/(b,n)
    const size_t plane6 = (size_t)BB * NN * (TT >> 6);   // GB=6: 32 partials/(b,n)
    const size_t segN   = (size_t)BB * SEGS * TT;

    if (ws_size >= (3 * plane4 + segN) * sizeof(float)) {
        // ~55 MB path: SEG=16, GB=4 (DPP-only reductions)
        float* mP = (float*)d_ws;
        float* sP = mP + plane4;
        float* pP = sP + plane4;
        float* sg = pP + plane4;
        segsum_kernel<SEGS><<<BB * CHUNKS * SEGS, 256, 0, stream>>>(data, targets, W, sg);
        scan_kernel<SEGS, 4><<<BB * CHUNKS * SEGS, 256, 0, stream>>>(data, targets, W, sg, mP, sP, pP);
        combine_kernel<128><<<(BB * NN) / 4, 256, 0, stream>>>(mP, sP, pP, out);
    } else if (ws_size >= (3 * plane6 + segN) * sizeof(float)) {
        // ~17 MB path: SEG=16, GB=6
        float* mP = (float*)d_ws;
        float* sP = mP + plane6;
        float* pP = sP + plane6;
        float* sg = pP + plane6;
        segsum_kernel<SEGS><<<BB * CHUNKS * SEGS, 256, 0, stream>>>(data, targets, W, sg);
        scan_kernel<SEGS, 6><<<BB * CHUNKS * SEGS, 256, 0, stream>>>(data, targets, W, sg, mP, sP, pP);
        combine_kernel<32><<<(BB * NN) / 4, 256, 0, stream>>>(mP, sP, pP, out);
    } else {
        // 12 MB fallback: no segmentation (slow but correct)
        float* mP = (float*)d_ws;
        float* sP = mP + plane6;
        float* pP = sP + plane6;
        scan_kernel<1, 6><<<BB * CHUNKS, 256, 0, stream>>>(data, targets, W, nullptr, mP, sP, pP);
        combine_kernel<32><<<(BB * NN) / 4, 256, 0, stream>>>(mP, sP, pP, out);
    }
}

// Round 7
// 315.349 us; speedup vs baseline: 1.4714x; 1.0945x over previous
//
#include <hip/hip_runtime.h>
#include <hip/hip_bf16.h>
#include <math.h>

// Problem constants (from reference setup_inputs)
#define BB 32
#define NN 1024
#define DD 64
#define TT 2048
#define CHUNKS (TT / 256)   // 8 column-chunks of 256
#define SEGS 16             // n-segments (decoupled scan)

typedef float f32x4 __attribute__((ext_vector_type(4)));

// DPP move WITHOUT tied-old operand -> LLVM fuses it into the consuming
// v_max/v_add as a DPP modifier (1 inst per tree step instead of 3).
template<int CTRL>
__device__ __forceinline__ float dpp_mov_f(float v) {
    return __int_as_float(
        __builtin_amdgcn_mov_dpp(__float_as_int(v), CTRL, 0xF, 0xF, true));
}

// All-lanes butterfly reduce over groups of 2^GB lanes.
// GB=4: pure-VALU DPP (xor1, xor2, half-mirror=xor4, mirror=xor8).
// GB=6: adds two LDS shuffles (xor16, xor32).
template<int GB>
__device__ __forceinline__ float groupMax(float v) {
    v = fmaxf(v, dpp_mov_f<0x0B1>(v));  // quad_perm [1,0,3,2]  -> xor1
    v = fmaxf(v, dpp_mov_f<0x04E>(v));  // quad_perm [2,3,0,1]  -> xor2
    v = fmaxf(v, dpp_mov_f<0x141>(v));  // row_half_mirror      -> xor4
    v = fmaxf(v, dpp_mov_f<0x140>(v));  // row_mirror           -> xor8
    if constexpr (GB == 6) {
        v = fmaxf(v, __shfl_xor(v, 16));
        v = fmaxf(v, __shfl_xor(v, 32));
    }
    return v;
}

template<int GB>
__device__ __forceinline__ float groupSum(float v) {
    v += dpp_mov_f<0x0B1>(v);
    v += dpp_mov_f<0x04E>(v);
    v += dpp_mov_f<0x141>(v);
    v += dpp_mov_f<0x140>(v);
    if constexpr (GB == 6) {
        v += __shfl_xor(v, 16);
        v += __shfl_xor(v, 32);
    }
    return v;
}

__device__ __forceinline__ void loadW(const float* __restrict__ W, int col,
                                      f32x4* wv) {
#pragma unroll
    for (int i = 0; i < 16; ++i) {
        wv[i].x = W[(size_t)(4 * i + 0) * TT + col];
        wv[i].y = W[(size_t)(4 * i + 1) * TT + col];
        wv[i].z = W[(size_t)(4 * i + 2) * TT + col];
        wv[i].w = W[(size_t)(4 * i + 3) * TT + col];
    }
}

// horizontal sum with the SAME association as the original dot64:
// (a0+a1)+(a2+a3) where a_k accumulated d = k, k+4, k+8, ...
__device__ __forceinline__ float hsum(f32x4 s) {
    return (s.x + s.y) + (s.z + s.w);
}

// 4 independent dots vs the same W column; one W read feeds 4 FMAs.
__device__ __forceinline__ void dot4(const float* __restrict__ x0p,
                                     const f32x4* wv,
                                     float& xw0, float& xw1,
                                     float& xw2, float& xw3) {
    const f32x4* xr0 = (const f32x4*)(x0p);
    const f32x4* xr1 = (const f32x4*)(x0p + DD);
    const f32x4* xr2 = (const f32x4*)(x0p + 2 * DD);
    const f32x4* xr3 = (const f32x4*)(x0p + 3 * DD);
    f32x4 s0 = {0.f, 0.f, 0.f, 0.f};
    f32x4 s1 = {0.f, 0.f, 0.f, 0.f};
    f32x4 s2 = {0.f, 0.f, 0.f, 0.f};
    f32x4 s3 = {0.f, 0.f, 0.f, 0.f};
#pragma unroll
    for (int i = 0; i < 16; ++i) {
        const f32x4 w = wv[i];
        s0 += xr0[i] * w;
        s1 += xr1[i] * w;
        s2 += xr2[i] * w;
        s3 += xr3[i] * w;
    }
    xw0 = hsum(s0); xw1 = hsum(s1); xw2 = hsum(s2); xw3 = hsum(s3);
}

// Pass A: per-(b, t, segment) sum of log-probs. Fully parallel over segments.
// Measured at its VALU issue floor (~65 us) in R5 — do not touch.
template<int SEG>
__global__ __launch_bounds__(256, 4)
void segsum_kernel(const float* __restrict__ data,
                   const float* __restrict__ targets,
                   const float* __restrict__ W,
                   float* __restrict__ segsum)
{
    constexpr int NSEG = NN / SEG;
    const int blk   = blockIdx.x;
    const int s     = blk % SEG;
    const int rem   = blk / SEG;
    const int chunk = rem % CHUNKS;
    const int b     = rem / CHUNKS;
    const int tid   = threadIdx.x;
    const int col   = chunk * 256 + tid;

    f32x4 wv[16];
    loadW(W, col, wv);

    const float* xb = data + (size_t)b * NN * DD;
    const float* tb = targets + (size_t)b * NN;

    const int n0 = s * NSEG;
    float acc = 0.0f;
    for (int n = n0; n < n0 + NSEG; n += 4) {
        float xw0, xw1, xw2, xw3;
        dot4(xb + (size_t)n * DD, wv, xw0, xw1, xw2, xw3);
        const float t0 = tb[n], t1 = tb[n + 1], t2 = tb[n + 2], t3 = tb[n + 3];
        const float d0 = t0 - xw0;  acc = fmaf(d0 * d0, -0.5f, acc);
        const float d1 = t1 - xw1;  acc = fmaf(d1 * d1, -0.5f, acc);
        const float d2 = t2 - xw2;  acc = fmaf(d2 * d2, -0.5f, acc);
        const float d3 = t3 - xw3;  acc = fmaf(d3 * d3, -0.5f, acc);
    }
    segsum[((size_t)b * SEG + s) * TT + col] = acc;
}

// Pass B: per-(b, t-chunk, segment) local scan seeded with segment prefix.
// Batched-4 phases for ILP, but PER-POINT max trees (m_j = groupMax(a_j)):
// the argmax lane always contributes e=1, so group sums never underflow to
// zero (R6's shared-max NaN'd exactly this way). Values are bitwise equal
// to the R5 formulation.
template<int SEG, int GB>
__global__ __launch_bounds__(256, 4)
void scan_kernel(const float* __restrict__ data,
                 const float* __restrict__ targets,
                 const float* __restrict__ W,
                 const float* __restrict__ segsum,
                 float* __restrict__ mP,
                 float* __restrict__ sP,
                 float* __restrict__ pP)
{
    constexpr int NSEG = NN / SEG;
    constexpr int PPN  = TT >> GB;            // partials per (b,n)
    const int blk   = blockIdx.x;
    const int s     = blk % SEG;
    const int rem   = blk / SEG;
    const int chunk = rem % CHUNKS;
    const int b     = rem / CHUNKS;
    const int tid   = threadIdx.x;
    const int lane  = tid & 63;
    const int col   = chunk * 256 + tid;

    f32x4 wv[16];
    loadW(W, col, wv);

    const float* xb = data + (size_t)b * NN * DD;
    const float* tb = targets + (size_t)b * NN;

    const int  k      = (chunk * 256 + (tid & ~((1 << GB) - 1))) >> GB;
    const bool writer = (lane & ((1 << GB) - 1)) == 0;
    const size_t base0 = (size_t)b * NN * PPN + k;

    // exclusive segment prefix
    float alpha = 0.0f;
    if constexpr (SEG > 1) {
        for (int s2 = 0; s2 < s; ++s2)
            alpha += segsum[((size_t)b * SEG + s2) * TT + col];
    }

    const int n0 = s * NSEG;
    for (int n = n0; n < n0 + NSEG; n += 4) {
        float xw0, xw1, xw2, xw3;
        dot4(xb + (size_t)n * DD, wv, xw0, xw1, xw2, xw3);

        // Phase 1: exclusive alphas for the 4 points (short serial chain).
        const float a0 = alpha;
        const float d0 = tb[n + 0] - xw0;  const float a1 = fmaf(d0 * d0, -0.5f, a0);
        const float d1 = tb[n + 1] - xw1;  const float a2 = fmaf(d1 * d1, -0.5f, a1);
        const float d2 = tb[n + 2] - xw2;  const float a3 = fmaf(d2 * d2, -0.5f, a2);
        const float d3 = tb[n + 3] - xw3;  alpha          = fmaf(d3 * d3, -0.5f, a3);

        // Phase 2: four independent per-point max trees (ILP-overlapped).
        const float m0 = groupMax<GB>(a0);
        const float m1 = groupMax<GB>(a1);
        const float m2 = groupMax<GB>(a2);
        const float m3 = groupMax<GB>(a3);

        // Phase 3: exps + weighted values (independent).
        const float e0 = __expf(a0 - m0);
        const float e1 = __expf(a1 - m1);
        const float e2 = __expf(a2 - m2);
        const float e3 = __expf(a3 - m3);
        const float q0 = e0 * xw0, q1 = e1 * xw1, q2 = e2 * xw2, q3 = e3 * xw3;

        // Phase 4: 8 independent sum trees (ILP across points).
        const float sv0 = groupSum<GB>(e0);
        const float sv1 = groupSum<GB>(e1);
        const float sv2 = groupSum<GB>(e2);
        const float sv3 = groupSum<GB>(e3);
        const float pv0 = groupSum<GB>(q0);
        const float pv1 = groupSum<GB>(q1);
        const float pv2 = groupSum<GB>(q2);
        const float pv3 = groupSum<GB>(q3);

        // Phase 5: one writer block per 4 points. Consecutive idx differ by
        // PPN -> compiler folds into immediate-offset stores off one base.
        if (writer) {
            const size_t i0 = base0 + (size_t)(n + 0) * PPN;
            const size_t i1 = i0 + PPN;
            const size_t i2 = i0 + 2 * PPN;
            const size_t i3 = i0 + 3 * PPN;
            mP[i0] = m0;  sP[i0] = sv0;  pP[i0] = pv0;
            mP[i1] = m1;  sP[i1] = sv1;  pP[i1] = pv1;
            mP[i2] = m2;  sP[i2] = sv2;  pP[i2] = pv2;
            mP[i3] = m3;  sP[i3] = sv3;  pP[i3] = pv3;
        }
    }
}

// Pass C: one wave per (b,n): merge PPN partials with log-sum-exp combine.
template<int PPN>
__global__ __launch_bounds__(256)
void combine_kernel(const float* __restrict__ mP,
                    const float* __restrict__ sP,
                    const float* __restrict__ pP,
                    float* __restrict__ out)
{
    const int wgid = blockIdx.x * 4 + (threadIdx.x >> 6);   // = b*NN + n
    const int lane = threadIdx.x & 63;
    const size_t base = (size_t)wgid * PPN;

    float m = -INFINITY, s = 0.0f, p = 0.0f;
    if constexpr (PPN >= 64) {
#pragma unroll
        for (int j = 0; j < PPN / 64; ++j) {
            const size_t idx = base + lane + j * 64;
            const float mk = mP[idx], sk = sP[idx], pk = pP[idx];
            const float M  = fmaxf(m, mk);
            const float e1 = __expf(m - M), e2 = __expf(mk - M);
            s = s * e1 + sk * e2;
            p = p * e1 + pk * e2;
            m = M;
        }
    } else {
        if (lane < PPN) {
            m = mP[base + lane]; s = sP[base + lane]; p = pP[base + lane];
        }
    }

#pragma unroll
    for (int off = 1; off < 64; off <<= 1) {
        const float mo = __shfl_xor(m, off);
        const float so = __shfl_xor(s, off);
        const float po = __shfl_xor(p, off);
        const float M  = fmaxf(m, mo);
        const float e1 = __expf(m - M), e2 = __expf(mo - M);
        s = s * e1 + so * e2;
        p = p * e1 + po * e2;
        m = M;
    }

    if (lane == 0) out[wgid] = p / s;
}

extern "C" void kernel_launch(void* const* d_in, const int* in_sizes, int n_in,
                              void* d_out, int out_size, void* d_ws, size_t ws_size,
                              hipStream_t stream)
{
    (void)in_sizes; (void)n_in; (void)out_size;
    const float* data    = (const float*)d_in[0];
    const float* targets = (const float*)d_in[1];
    const float* W       = (const float*)d_in[2];
    float* out = (float*)d_out;

    const size_t plane4 = (size_t)BB * NN * (TT >> 4);   // GB=4: 128 partials/(b,n)
    const size_t plane6 = (size_t)BB * NN * (TT >> 6);   // GB=6: 32 partials/(b,n)
    const size_t segN   = (size_t)BB * SEGS * TT;

    if (ws_size >= (3 * plane4 + segN) * sizeof(float)) {
        // ~52 MB path: SEG=16, GB=4 (DPP-only reductions)
        float* mP = (float*)d_ws;
        float* sP = mP + plane4;
        float* pP = sP + plane4;
        float* sg = pP + plane4;
        segsum_kernel<SEGS><<<BB * CHUNKS * SEGS, 256, 0, stream>>>(data, targets, W, sg);
        scan_kernel<SEGS, 4><<<BB * CHUNKS * SEGS, 256, 0, stream>>>(data, targets, W, sg, mP, sP, pP);
        combine_kernel<128><<<(BB * NN) / 4, 256, 0, stream>>>(mP, sP, pP, out);
    } else if (ws_size >= (3 * plane6 + segN) * sizeof(float)) {
        // ~17 MB path: SEG=16, GB=6
        float* mP = (float*)d_ws;
        float* sP = mP + plane6;
        float* pP = sP + plane6;
        float* sg = pP + plane6;
        segsum_kernel<SEGS><<<BB * CHUNKS * SEGS, 256, 0, stream>>>(data, targets, W, sg);
        scan_kernel<SEGS, 6><<<BB * CHUNKS * SEGS, 256, 0, stream>>>(data, targets, W, sg, mP, sP, pP);
        combine_kernel<32><<<(BB * NN) / 4, 256, 0, stream>>>(mP, sP, pP, out);
    } else {
        // 12 MB fallback: no segmentation (slow but correct)
        float* mP = (float*)d_ws;
        float* sP = mP + plane6;
        float* pP = sP + plane6;
        scan_kernel<1, 6><<<BB * CHUNKS, 256, 0, stream>>>(data, targets, W, nullptr, mP, sP, pP);
        combine_kernel<32><<<(BB * NN) / 4, 256, 0, stream>>>(mP, sP, pP, out);
    }
}